// Round 1
// baseline (737.600 us; speedup 1.0000x reference)
//
#include <hip/hip_runtime.h>

#define VOCAB 50257
#define EMBED 512
#define HID   512
#define B     128
#define SRC   128

// ---------------------------------------------------------------------------
// K1: rnn_in[b] = concat(embedding[x[b]], context_vec[b])   [B][1024]
// ---------------------------------------------------------------------------
__global__ void k_embed_concat(const int* __restrict__ x,
                               const float* __restrict__ ctxv,
                               const float* __restrict__ emb,
                               float* __restrict__ rnn_in) {
    int b = blockIdx.x;
    int row = x[b];
    const float4* e = (const float4*)(emb + (size_t)row * EMBED);
    const float4* c = (const float4*)(ctxv + (size_t)b * HID);
    float4* o = (float4*)(rnn_in + (size_t)b * (EMBED + HID));
    for (int i = threadIdx.x; i < EMBED / 4; i += blockDim.x) o[i] = e[i];
    for (int i = threadIdx.x; i < HID / 4; i += blockDim.x) o[EMBED / 4 + i] = c[i];
}

// ---------------------------------------------------------------------------
// K2: generic small GEMM  C[M][N] = act(A[M][K] @ W[N][K]^T + bias)
// thread = one n column, 4 batch rows. A rows read wave-uniformly (s_load).
// grid = (N/256, M/4), block = 256.
// ---------------------------------------------------------------------------
template <int ACT>  // 0 = none, 1 = tanh
__global__ void k_dot_gemm(const float* __restrict__ A, const float* __restrict__ W,
                           const float* __restrict__ bias, float* __restrict__ C,
                           int N, int K) {
    int n = blockIdx.x * 256 + threadIdx.x;
    int b0 = blockIdx.y * 4;
    int nc = n < N ? n : N - 1;
    const float* wr = W + (size_t)nc * K;
    const float* a0 = A + (size_t)(b0 + 0) * K;
    const float* a1 = A + (size_t)(b0 + 1) * K;
    const float* a2 = A + (size_t)(b0 + 2) * K;
    const float* a3 = A + (size_t)(b0 + 3) * K;
    float c0 = 0.f, c1 = 0.f, c2 = 0.f, c3 = 0.f;
    for (int k = 0; k < K; k += 4) {
        float4 w = *(const float4*)(wr + k);
        float4 v0 = *(const float4*)(a0 + k);
        float4 v1 = *(const float4*)(a1 + k);
        float4 v2 = *(const float4*)(a2 + k);
        float4 v3 = *(const float4*)(a3 + k);
        c0 = fmaf(w.x, v0.x, fmaf(w.y, v0.y, fmaf(w.z, v0.z, fmaf(w.w, v0.w, c0))));
        c1 = fmaf(w.x, v1.x, fmaf(w.y, v1.y, fmaf(w.z, v1.z, fmaf(w.w, v1.w, c1))));
        c2 = fmaf(w.x, v2.x, fmaf(w.y, v2.y, fmaf(w.z, v2.z, fmaf(w.w, v2.w, c2))));
        c3 = fmaf(w.x, v3.x, fmaf(w.y, v3.y, fmaf(w.z, v3.z, fmaf(w.w, v3.w, c3))));
    }
    if (n < N) {
        float bb = bias ? bias[n] : 0.0f;
        float r0 = c0 + bb, r1 = c1 + bb, r2 = c2 + bb, r3 = c3 + bb;
        if (ACT == 1) { r0 = tanhf(r0); r1 = tanhf(r1); r2 = tanhf(r2); r3 = tanhf(r3); }
        C[(size_t)(b0 + 0) * N + n] = r0;
        C[(size_t)(b0 + 1) * N + n] = r1;
        C[(size_t)(b0 + 2) * N + n] = r2;
        C[(size_t)(b0 + 3) * N + n] = r3;
    }
}

// ---------------------------------------------------------------------------
// K3: GRU gate combine (PyTorch order r,z,n)
// ---------------------------------------------------------------------------
__global__ void k_gru(const float* __restrict__ gi, const float* __restrict__ gh,
                      const float* __restrict__ h0, float* __restrict__ h) {
    int idx = blockIdx.x * blockDim.x + threadIdx.x;
    if (idx >= B * HID) return;
    int b = idx >> 9, j = idx & 511;
    const float* gib = gi + (size_t)b * 1536;
    const float* ghb = gh + (size_t)b * 1536;
    float ir = gib[j], iz = gib[512 + j], inn = gib[1024 + j];
    float hr = ghb[j], hz = ghb[512 + j], hn = ghb[1024 + j];
    float r = 1.f / (1.f + expf(-(ir + hr)));
    float z = 1.f / (1.f + expf(-(iz + hz)));
    float nn = tanhf(inn + r * hn);
    h[idx] = (1.f - z) * nn + z * h0[idx];
}

// ---------------------------------------------------------------------------
// K4: attention: scores -> mask -> softmax(axis=s) -> a[s][b], ctx;
//     also builds cat[b] = [ctx_pre | h]
// one block per batch row, 128 threads (thread = one s for scores, 4 h for ctx)
// ---------------------------------------------------------------------------
__global__ void k_attn(const float* __restrict__ enc, const float* __restrict__ q,
                       const int* __restrict__ lens, const float* __restrict__ h,
                       float* __restrict__ a_out, float* __restrict__ cat) {
    __shared__ float qs[HID];
    __shared__ float aw[SRC];
    __shared__ float red[SRC];
    int b = blockIdx.x, t = threadIdx.x;
    for (int i = t; i < HID; i += SRC) qs[i] = q[(size_t)b * HID + i];
    __syncthreads();
    const float4* er = (const float4*)(enc + ((size_t)b * SRC + t) * HID);
    float s = 0.f;
#pragma unroll 4
    for (int k = 0; k < HID / 4; ++k) {
        float4 e = er[k];
        float4 qq = *(const float4*)&qs[k * 4];
        s = fmaf(e.x, qq.x, fmaf(e.y, qq.y, fmaf(e.z, qq.z, fmaf(e.w, qq.w, s))));
    }
    int len = lens[b];
    float val = (t < len) ? s : 0.0f;
    if (val == 0.0f) val = -1e10f;          // replicate ref's where(masked==0,-1e10)
    red[t] = val; __syncthreads();
    for (int off = 64; off > 0; off >>= 1) {
        if (t < off) red[t] = fmaxf(red[t], red[t + off]);
        __syncthreads();
    }
    float mx = red[0]; __syncthreads();
    float e = expf(val - mx);
    red[t] = e; __syncthreads();
    for (int off = 64; off > 0; off >>= 1) {
        if (t < off) red[t] += red[t + off];
        __syncthreads();
    }
    float av = e / red[0];
    a_out[(size_t)t * B + b] = av;          // layout [S][B]
    aw[t] = av;
    __syncthreads();
    float4 accv = {0.f, 0.f, 0.f, 0.f};
    const float4* e4 = (const float4*)(enc + (size_t)b * SRC * HID);
    for (int s2 = 0; s2 < SRC; ++s2) {
        float w = aw[s2];
        float4 ev = e4[(size_t)s2 * (HID / 4) + t];
        accv.x = fmaf(w, ev.x, accv.x);
        accv.y = fmaf(w, ev.y, accv.y);
        accv.z = fmaf(w, ev.z, accv.z);
        accv.w = fmaf(w, ev.w, accv.w);
    }
    *(float4*)&cat[(size_t)b * 1024 + t * 4] = accv;
    *(float4*)&cat[(size_t)b * 1024 + 512 + t * 4] =
        *(const float4*)(h + (size_t)b * HID + t * 4);
}

// ---------------------------------------------------------------------------
// K5: fc1 GEMM  C[128][VOCAB] = ctx2[128][512] @ W[VOCAB][512]^T + bias
// block: 64 m x 128 n; thread: 4m x 8n; A staged in LDS (padded), W streamed.
// grid = (2, 393) -> m-half fastest so both halves share the W tile in L2.
// ---------------------------------------------------------------------------
__global__ __launch_bounds__(256, 4) void k_fc1(const float* __restrict__ A,
                                                const float* __restrict__ W,
                                                const float* __restrict__ bias,
                                                float* __restrict__ C) {
    __shared__ float As[64][132];
    const int tid = threadIdx.x;
    const int tn = tid & 15;
    const int tm = tid >> 4;
    const int m0 = blockIdx.x * 64;
    const int n0 = blockIdx.y * 128;
    float acc[4][8];
#pragma unroll
    for (int j = 0; j < 4; ++j)
#pragma unroll
        for (int i = 0; i < 8; ++i) acc[j][i] = 0.f;
    int nr[8];
#pragma unroll
    for (int i = 0; i < 8; ++i) {
        int n = n0 + tn * 8 + i;
        nr[i] = n < VOCAB ? n : VOCAB - 1;
    }
    for (int ks = 0; ks < 4; ++ks) {
        __syncthreads();
#pragma unroll
        for (int j = 0; j < 8; ++j) {       // stage 64m x 128k A tile
            int f4i = tid + j * 256;        // 0..2047
            int m = f4i >> 5;               // 0..63
            int kc = f4i & 31;              // 0..31
            float4 v = *(const float4*)(A + (size_t)(m0 + m) * 512 + ks * 128 + kc * 4);
            *(float4*)&As[m][kc * 4] = v;
        }
        __syncthreads();
        for (int k4 = 0; k4 < 32; ++k4) {
            float4 wv[8];
#pragma unroll
            for (int i = 0; i < 8; ++i)
                wv[i] = *(const float4*)(W + (size_t)nr[i] * 512 + ks * 128 + k4 * 4);
            float4 av[4];
#pragma unroll
            for (int j = 0; j < 4; ++j)
                av[j] = *(const float4*)&As[tm * 4 + j][k4 * 4];
#pragma unroll
            for (int j = 0; j < 4; ++j) {
#pragma unroll
                for (int i = 0; i < 8; ++i) {
                    acc[j][i] = fmaf(av[j].x, wv[i].x, acc[j][i]);
                    acc[j][i] = fmaf(av[j].y, wv[i].y, acc[j][i]);
                    acc[j][i] = fmaf(av[j].z, wv[i].z, acc[j][i]);
                    acc[j][i] = fmaf(av[j].w, wv[i].w, acc[j][i]);
                }
            }
        }
    }
#pragma unroll
    for (int i = 0; i < 8; ++i) {
        int n = n0 + tn * 8 + i;
        if (n < VOCAB) {
            float bb = bias[n];
#pragma unroll
            for (int j = 0; j < 4; ++j)
                C[(size_t)(m0 + tm * 4 + j) * VOCAB + n] = acc[j][i] + bb;
        }
    }
}

// ---------------------------------------------------------------------------
// K6: per-row logsumexp (online max/sum), L[b] = max + log(sumexp)
// ---------------------------------------------------------------------------
__global__ void k_lse(const float* __restrict__ logits, float* __restrict__ L) {
    int b = blockIdx.x, t = threadIdx.x;
    const float* row = logits + (size_t)b * VOCAB;
    float m = -1e30f, s = 0.f;
    for (int v = t; v < VOCAB; v += 256) {
        float x = row[v];
        if (x > m) { s = s * expf(m - x) + 1.f; m = x; }
        else        s += expf(x - m);
    }
    __shared__ float sm[256], ss[256];
    sm[t] = m; ss[t] = s; __syncthreads();
    for (int off = 128; off > 0; off >>= 1) {
        if (t < off) {
            float m2 = sm[t + off], s2 = ss[t + off];
            float mm = fmaxf(sm[t], m2);
            ss[t] = ss[t] * expf(sm[t] - mm) + s2 * expf(m2 - mm);
            sm[t] = mm;
        }
        __syncthreads();
    }
    if (t == 0) L[b] = sm[0] + logf(ss[0]);
}

// ---------------------------------------------------------------------------
// K7: log_probs = logits - L[b]  (in place)   grid = (50, 128)
// ---------------------------------------------------------------------------
__global__ void k_lsub(float* __restrict__ logits, const float* __restrict__ L) {
    int b = blockIdx.y;
    int off = blockIdx.x * 1024 + threadIdx.x * 4;
    float l = L[b];
    float* row = logits + (size_t)b * VOCAB;
#pragma unroll
    for (int j = 0; j < 4; ++j) {
        int v = off + j;
        if (v < VOCAB) row[v] -= l;
    }
}

// ---------------------------------------------------------------------------
extern "C" void kernel_launch(void* const* d_in, const int* in_sizes, int n_in,
                              void* d_out, int out_size, void* d_ws, size_t ws_size,
                              hipStream_t stream) {
    const int*   x    = (const int*)d_in[0];
    const float* h0   = (const float*)d_in[1];   // decoder_hidden [1,B,H]
    const int*   lens = (const int*)d_in[2];
    const float* enc  = (const float*)d_in[3];   // [B,SRC,H]
    const float* ctxv = (const float*)d_in[4];   // [B,H]
    const float* emb  = (const float*)d_in[5];   // [V,E]
    const float* wih  = (const float*)d_in[6];   // [1536,1024]
    const float* whh  = (const float*)d_in[7];   // [1536,512]
    const float* bih  = (const float*)d_in[8];
    const float* bhh  = (const float*)d_in[9];
    const float* Wa   = (const float*)d_in[10];  // [512,512]
    const float* Wc   = (const float*)d_in[11];  // [512,1024]
    const float* fc1w = (const float*)d_in[12];  // [V,512]
    const float* fc1b = (const float*)d_in[13];

    float* out     = (float*)d_out;
    float* outLogp = out;                                  // [B][VOCAB]
    float* outHid  = out + (size_t)B * VOCAB;              // [B][HID]
    float* outA    = outHid + (size_t)B * HID;             // [SRC][B]
    float* outCtx  = outA + (size_t)SRC * B;               // [B][HID]

    // scratch lives inside the not-yet-written log_probs region (6.4M floats);
    // fc1 overwrites all of it afterwards. Only L (128 f) uses d_ws.
    float* rnn_in = outLogp;                 // [B][1024]
    float* gi     = rnn_in + B * 1024;       // [B][1536]
    float* gh     = gi + B * 1536;           // [B][1536]
    float* q      = gh + B * 1536;           // [B][512]
    float* cat    = q + B * HID;             // [B][1024]
    float* L      = (float*)d_ws;            // [B]

    k_embed_concat<<<dim3(B), dim3(256), 0, stream>>>(x, ctxv, emb, rnn_in);
    k_dot_gemm<0><<<dim3(6, 32), dim3(256), 0, stream>>>(rnn_in, wih, bih, gi, 1536, 1024);
    k_dot_gemm<0><<<dim3(6, 32), dim3(256), 0, stream>>>(h0, whh, bhh, gh, 1536, 512);
    k_gru<<<dim3(256), dim3(256), 0, stream>>>(gi, gh, h0, outHid);
    k_dot_gemm<0><<<dim3(2, 32), dim3(256), 0, stream>>>(outHid, Wa, nullptr, q, 512, 512);
    k_attn<<<dim3(B), dim3(SRC), 0, stream>>>(enc, q, lens, outHid, outA, cat);
    k_dot_gemm<1><<<dim3(2, 32), dim3(256), 0, stream>>>(cat, Wc, nullptr, outCtx, 512, 1024);
    k_fc1<<<dim3(2, 393), dim3(256), 0, stream>>>(outCtx, fc1w, fc1b, outLogp);
    k_lse<<<dim3(B), dim3(256), 0, stream>>>(outLogp, L);
    k_lsub<<<dim3(50, B), dim3(256), 0, stream>>>(outLogp, L);
}

// Round 2
// 201.703 us; speedup vs baseline: 3.6569x; 3.6569x over previous
//
#include <hip/hip_runtime.h>

#define VOCAB 50257
#define EMBED 512
#define HID   512
#define B     128
#define SRC   128

typedef __attribute__((ext_vector_type(8))) short short8;
typedef __attribute__((ext_vector_type(4))) float f32x4;

// f32 -> bf16 (round-to-nearest-even), result in low 16 bits
__device__ __forceinline__ unsigned f2bf(float x) {
    unsigned u = __builtin_bit_cast(unsigned, x);
    return (u + 0x7fffu + ((u >> 16) & 1u)) >> 16;
}
__device__ __forceinline__ unsigned pk2(float lo, float hi) {
    return f2bf(lo) | (f2bf(hi) << 16);
}

// ---------------------------------------------------------------------------
// K1: rnn_in[b] = concat(embedding[x[b]], context_vec[b])   [B][1024]
// ---------------------------------------------------------------------------
__global__ void k_embed_concat(const int* __restrict__ x,
                               const float* __restrict__ ctxv,
                               const float* __restrict__ emb,
                               float* __restrict__ rnn_in) {
    int b = blockIdx.x;
    int row = x[b];
    const float4* e = (const float4*)(emb + (size_t)row * EMBED);
    const float4* c = (const float4*)(ctxv + (size_t)b * HID);
    float4* o = (float4*)(rnn_in + (size_t)b * (EMBED + HID));
    for (int i = threadIdx.x; i < EMBED / 4; i += blockDim.x) o[i] = e[i];
    for (int i = threadIdx.x; i < HID / 4; i += blockDim.x) o[EMBED / 4 + i] = c[i];
}

// ---------------------------------------------------------------------------
// K2: MFMA GEMM  C[128][N] = act(A[128][K] @ W[N][K]^T + bias), bf16 inputs
// converted on the fly (RNE). Block = 4 waves, 64 n-cols (16/wave), all 128 m.
// A staged per-256-K-chunk into LDS in MFMA fragment order (conflict-free
// lane-contiguous ds_read_b128). W streamed coalesced (128B/row segments).
// mfma_f32_16x16x32_bf16: A-frag lane: row=l&15, k=(l>>4)*8+j;
//                         B-frag lane: col=l&15, k=(l>>4)*8+j;
//                         D: col=l&15, row=(l>>4)*4+reg   [m89/m91 verified]
// ---------------------------------------------------------------------------
template <int N, int K, int ACT, int HASB>
__global__ __launch_bounds__(256, 2) void k_mfma_gemm(
        const float* __restrict__ A, const float* __restrict__ W,
        const float* __restrict__ bias, float* __restrict__ C) {
    __shared__ uint4 As[4096];  // 64KB: [mt(8)][ks(8)][lane(64)] 16B frags
    const int tid = threadIdx.x;
    const int lane = tid & 63;
    const int wv = tid >> 6;
    const int n0w = blockIdx.x * 64 + wv * 16;
    const int ncol = n0w + (lane & 15);
    const int nc = ncol < N ? ncol : N - 1;   // clamp for tail loads
    const int kg = lane >> 4;

    f32x4 acc[8];
#pragma unroll
    for (int mt = 0; mt < 8; ++mt) acc[mt] = (f32x4)0.f;

    const int NCH = K / 256;
    for (int kc = 0; kc < NCH; ++kc) {
        if (kc) __syncthreads();
        // stage A chunk [128][256] f32 -> bf16 fragment layout
#pragma unroll
        for (int it = 0; it < 16; ++it) {
            int f = tid + it * 256;
            int mt = f >> 9, ks = (f >> 6) & 7, l = f & 63;
            const float* ap = A + (size_t)(mt * 16 + (l & 15)) * K
                              + kc * 256 + ks * 32 + (l >> 4) * 8;
            float4 a0 = *(const float4*)ap;
            float4 a1 = *(const float4*)(ap + 4);
            uint4 p;
            p.x = pk2(a0.x, a0.y); p.y = pk2(a0.z, a0.w);
            p.z = pk2(a1.x, a1.y); p.w = pk2(a1.z, a1.w);
            As[f] = p;
        }
        __syncthreads();
        const float* wbase = W + (size_t)nc * K + kc * 256 + kg * 8;
        for (int ks = 0; ks < 8; ++ks) {
            const float* wp = wbase + ks * 32;
            float4 w0 = *(const float4*)wp;
            float4 w1 = *(const float4*)(wp + 4);
            uint4 pb;
            pb.x = pk2(w0.x, w0.y); pb.y = pk2(w0.z, w0.w);
            pb.z = pk2(w1.x, w1.y); pb.w = pk2(w1.z, w1.w);
            short8 bf = __builtin_bit_cast(short8, pb);
#pragma unroll
            for (int mt = 0; mt < 8; ++mt) {
                short8 af = __builtin_bit_cast(short8, As[(mt * 8 + ks) * 64 + lane]);
                acc[mt] = __builtin_amdgcn_mfma_f32_16x16x32_bf16(af, bf, acc[mt], 0, 0, 0);
            }
        }
    }
    if (ncol < N) {
        float bb = HASB ? bias[ncol] : 0.f;
        const int r0 = (lane >> 4) * 4;
#pragma unroll
        for (int mt = 0; mt < 8; ++mt) {
#pragma unroll
            for (int j = 0; j < 4; ++j) {
                float v = acc[mt][j] + bb;
                if (ACT) v = tanhf(v);
                C[(size_t)(mt * 16 + r0 + j) * N + ncol] = v;
            }
        }
    }
}

// ---------------------------------------------------------------------------
// K3: GRU gate combine (PyTorch order r,z,n)
// ---------------------------------------------------------------------------
__global__ void k_gru(const float* __restrict__ gi, const float* __restrict__ gh,
                      const float* __restrict__ h0, float* __restrict__ h) {
    int idx = blockIdx.x * blockDim.x + threadIdx.x;
    if (idx >= B * HID) return;
    int b = idx >> 9, j = idx & 511;
    const float* gib = gi + (size_t)b * 1536;
    const float* ghb = gh + (size_t)b * 1536;
    float ir = gib[j], iz = gib[512 + j], inn = gib[1024 + j];
    float hr = ghb[j], hz = ghb[512 + j], hn = ghb[1024 + j];
    float r = 1.f / (1.f + expf(-(ir + hr)));
    float z = 1.f / (1.f + expf(-(iz + hz)));
    float nn = tanhf(inn + r * hn);
    h[idx] = (1.f - z) * nn + z * h0[idx];
}

// ---------------------------------------------------------------------------
// K4: attention: scores -> mask -> softmax(axis=s) -> a[s][b], ctx;
//     also builds cat[b] = [ctx_pre | h]
// ---------------------------------------------------------------------------
__global__ void k_attn(const float* __restrict__ enc, const float* __restrict__ q,
                       const int* __restrict__ lens, const float* __restrict__ h,
                       float* __restrict__ a_out, float* __restrict__ cat) {
    __shared__ float qs[HID];
    __shared__ float aw[SRC];
    __shared__ float red[SRC];
    int b = blockIdx.x, t = threadIdx.x;
    for (int i = t; i < HID; i += SRC) qs[i] = q[(size_t)b * HID + i];
    __syncthreads();
    const float4* er = (const float4*)(enc + ((size_t)b * SRC + t) * HID);
    float s = 0.f;
#pragma unroll 4
    for (int k = 0; k < HID / 4; ++k) {
        float4 e = er[k];
        float4 qq = *(const float4*)&qs[k * 4];
        s = fmaf(e.x, qq.x, fmaf(e.y, qq.y, fmaf(e.z, qq.z, fmaf(e.w, qq.w, s))));
    }
    int len = lens[b];
    float val = (t < len) ? s : 0.0f;
    if (val == 0.0f) val = -1e10f;          // replicate ref's where(masked==0,-1e10)
    red[t] = val; __syncthreads();
    for (int off = 64; off > 0; off >>= 1) {
        if (t < off) red[t] = fmaxf(red[t], red[t + off]);
        __syncthreads();
    }
    float mx = red[0]; __syncthreads();
    float e = expf(val - mx);
    red[t] = e; __syncthreads();
    for (int off = 64; off > 0; off >>= 1) {
        if (t < off) red[t] += red[t + off];
        __syncthreads();
    }
    float av = e / red[0];
    a_out[(size_t)t * B + b] = av;          // layout [S][B]
    aw[t] = av;
    __syncthreads();
    float4 accv = {0.f, 0.f, 0.f, 0.f};
    const float4* e4 = (const float4*)(enc + (size_t)b * SRC * HID);
    for (int s2 = 0; s2 < SRC; ++s2) {
        float w = aw[s2];
        float4 ev = e4[(size_t)s2 * (HID / 4) + t];
        accv.x = fmaf(w, ev.x, accv.x);
        accv.y = fmaf(w, ev.y, accv.y);
        accv.z = fmaf(w, ev.z, accv.z);
        accv.w = fmaf(w, ev.w, accv.w);
    }
    *(float4*)&cat[(size_t)b * 1024 + t * 4] = accv;
    *(float4*)&cat[(size_t)b * 1024 + 512 + t * 4] =
        *(const float4*)(h + (size_t)b * HID + t * 4);
}

// ---------------------------------------------------------------------------
// K5: fused log-softmax: per-row online LSE then in-place subtract.
// One block per row; pass 2 re-reads the row from L2.
// ---------------------------------------------------------------------------
__global__ __launch_bounds__(1024) void k_lse_sub(float* __restrict__ logits) {
    const int b = blockIdx.x, t = threadIdx.x;
    float* row = logits + (size_t)b * VOCAB;
    const int N4 = VOCAB >> 2;  // 12564; one scalar tail element (50256)
    float m = -1e30f, s = 0.f;
    for (int i = t; i < N4; i += 1024) {
        float4 x = ((const float4*)row)[i];
        float xs[4] = {x.x, x.y, x.z, x.w};
#pragma unroll
        for (int j = 0; j < 4; ++j) {
            float v = xs[j];
            if (v > m) { s = s * __expf(m - v) + 1.f; m = v; }
            else        s += __expf(v - m);
        }
    }
    if (t == 0) {
        float v = row[VOCAB - 1];
        if (v > m) { s = s * __expf(m - v) + 1.f; m = v; }
        else        s += __expf(v - m);
    }
    __shared__ float sm[1024], ss[1024];
    sm[t] = m; ss[t] = s;
    __syncthreads();
    for (int off = 512; off > 0; off >>= 1) {
        if (t < off) {
            float m2 = sm[t + off], s2 = ss[t + off];
            float mm = fmaxf(sm[t], m2);
            ss[t] = ss[t] * __expf(sm[t] - mm) + s2 * __expf(m2 - mm);
            sm[t] = mm;
        }
        __syncthreads();
    }
    __shared__ float Lsh;
    if (t == 0) Lsh = sm[0] + logf(ss[0]);
    __syncthreads();
    float L = Lsh;
    for (int i = t; i < N4; i += 1024) {
        float4 x = ((const float4*)row)[i];
        x.x -= L; x.y -= L; x.z -= L; x.w -= L;
        ((float4*)row)[i] = x;
    }
    if (t == 0) row[VOCAB - 1] -= L;
}

// ---------------------------------------------------------------------------
extern "C" void kernel_launch(void* const* d_in, const int* in_sizes, int n_in,
                              void* d_out, int out_size, void* d_ws, size_t ws_size,
                              hipStream_t stream) {
    const int*   x    = (const int*)d_in[0];
    const float* h0   = (const float*)d_in[1];   // decoder_hidden [1,B,H]
    const int*   lens = (const int*)d_in[2];
    const float* enc  = (const float*)d_in[3];   // [B,SRC,H]
    const float* ctxv = (const float*)d_in[4];   // [B,H]
    const float* emb  = (const float*)d_in[5];   // [V,E]
    const float* wih  = (const float*)d_in[6];   // [1536,1024]
    const float* whh  = (const float*)d_in[7];   // [1536,512]
    const float* bih  = (const float*)d_in[8];
    const float* bhh  = (const float*)d_in[9];
    const float* Wa   = (const float*)d_in[10];  // [512,512]
    const float* Wc   = (const float*)d_in[11];  // [512,1024]
    const float* fc1w = (const float*)d_in[12];  // [V,512]
    const float* fc1b = (const float*)d_in[13];

    float* out     = (float*)d_out;
    float* outLogp = out;                                  // [B][VOCAB]
    float* outHid  = out + (size_t)B * VOCAB;              // [B][HID]
    float* outA    = outHid + (size_t)B * HID;             // [SRC][B]
    float* outCtx  = outA + (size_t)SRC * B;               // [B][HID]

    // scratch lives inside the not-yet-written log_probs region (6.4M floats);
    // fc1 overwrites all of it afterwards (and reads only outCtx, beyond it).
    float* rnn_in = outLogp;                 // [B][1024]
    float* gi     = rnn_in + B * 1024;       // [B][1536]
    float* gh     = gi + B * 1536;           // [B][1536]
    float* q      = gh + B * 1536;           // [B][512]
    float* cat    = q + B * HID;             // [B][1024]

    k_embed_concat<<<dim3(B), dim3(256), 0, stream>>>(x, ctxv, emb, rnn_in);
    k_mfma_gemm<1536, 1024, 0, 1><<<dim3(24), dim3(256), 0, stream>>>(rnn_in, wih, bih, gi);
    k_mfma_gemm<1536, 512, 0, 1><<<dim3(24), dim3(256), 0, stream>>>(h0, whh, bhh, gh);
    k_gru<<<dim3(256), dim3(256), 0, stream>>>(gi, gh, h0, outHid);
    k_mfma_gemm<512, 512, 0, 0><<<dim3(8), dim3(256), 0, stream>>>(outHid, Wa, nullptr, q);
    k_attn<<<dim3(B), dim3(SRC), 0, stream>>>(enc, q, lens, outHid, outA, cat);
    k_mfma_gemm<512, 1024, 1, 0><<<dim3(8), dim3(256), 0, stream>>>(cat, Wc, nullptr, outCtx);
    k_mfma_gemm<VOCAB, 512, 0, 1><<<dim3(786), dim3(256), 0, stream>>>(outCtx, fc1w, fc1b, outLogp);
    k_lse_sub<<<dim3(B), dim3(1024), 0, stream>>>(outLogp);
}

// Round 4
// 179.717 us; speedup vs baseline: 4.1042x; 1.1223x over previous
//
#include <hip/hip_runtime.h>

#define VOCAB 50257
#define EMBED 512
#define HID   512
#define B     128
#define SRC   128

typedef __attribute__((ext_vector_type(8))) short short8;
typedef __attribute__((ext_vector_type(4))) float f32x4;

// f32 -> bf16 (round-to-nearest-even), result in low 16 bits
__device__ __forceinline__ unsigned f2bf(float x) {
    unsigned u = __builtin_bit_cast(unsigned, x);
    return (u + 0x7fffu + ((u >> 16) & 1u)) >> 16;
}
__device__ __forceinline__ unsigned pk2(float lo, float hi) {
    return f2bf(lo) | (f2bf(hi) << 16);
}
__device__ __forceinline__ uint4 pk8(const float* p) {
    uint4 r;
    r.x = pk2(p[0], p[1]); r.y = pk2(p[2], p[3]);
    r.z = pk2(p[4], p[5]); r.w = pk2(p[6], p[7]);
    return r;
}
__device__ __forceinline__ uint4 pk8v(float4 a, float4 b) {
    uint4 r;
    r.x = pk2(a.x, a.y); r.y = pk2(a.z, a.w);
    r.z = pk2(b.x, b.y); r.w = pk2(b.z, b.w);
    return r;
}
__device__ __forceinline__ void gll16(const void* g, void* l) {
    __builtin_amdgcn_global_load_lds(
        (const __attribute__((address_space(1))) void*)g,
        (__attribute__((address_space(3))) void*)l, 16, 0, 0);
}

// Fragment-packed A layout (bf16, mfma_f32_16x16x32_bf16 A-operand order):
// uint4 index = ((kc*8 + mt)*4 + ksl)*64 + kg*16 + (row&15)
//   row = mt*16 + (row&15), k = kc*128 + ksl*32 + kg*8 + j (j=0..7)
// Each 128-k chunk (kc) is a contiguous 2048-uint4 (32KB) block.

// ---------------------------------------------------------------------------
// K1: pack rnn_in = [emb(x[b]) | ctxv[b]]  (K=1024) and h0[b]  (K=512)
// ---------------------------------------------------------------------------
__global__ void k_embed_pack(const int* __restrict__ x, const float* __restrict__ ctxv,
                             const float* __restrict__ emb, const float* __restrict__ h0,
                             uint4* __restrict__ apk_rnn, uint4* __restrict__ apk_h0) {
    __shared__ float buf[1024];
    __shared__ float hbuf[512];
    const int b = blockIdx.x, t = threadIdx.x;
    const int row = x[b];
    if (t < 128) {
        ((float4*)buf)[t]  = ((const float4*)(emb + (size_t)row * EMBED))[t];
        ((float4*)hbuf)[t] = ((const float4*)(h0 + (size_t)b * HID))[t];
    } else {
        ((float4*)buf)[t] = ((const float4*)(ctxv + (size_t)b * HID))[t - 128];
    }
    __syncthreads();
    const int mt = b >> 4, lb = b & 15;
    if (t < 128) {                       // rnn frag t (K=1024)
        int kc = t >> 4, ksl = (t >> 2) & 3, kg = t & 3;
        apk_rnn[((kc * 8 + mt) * 4 + ksl) * 64 + kg * 16 + lb] = pk8(&buf[t * 8]);
    } else if (t < 192) {                // h0 frag (K=512)
        int i = t - 128;
        int kc = i >> 4, ksl = (i >> 2) & 3, kg = i & 3;
        apk_h0[((kc * 8 + mt) * 4 + ksl) * 64 + kg * 16 + lb] = pk8(&hbuf[i * 8]);
    }
}

// ---------------------------------------------------------------------------
// K2: LDS-free MFMA GEMM, 1 wave per block, 16 cols/block, all 128 m.
// A-fragments read directly from pre-packed global (L2-hot, 1KB coalesced).
// Optional PACK: also emit this kernel's f32 output re-packed as fragments
// (for the following GEMM), via a small LDS transpose.
// ---------------------------------------------------------------------------
template <int N, int K, int ACT, int HASB, int PACK>
__global__ __launch_bounds__(64, 4) void k_gemm_direct(
        const uint4* __restrict__ apk, const float* __restrict__ W,
        const float* __restrict__ bias, float* __restrict__ C,
        uint4* __restrict__ apk_out) {
    const int lane = threadIdx.x;
    const int n0 = blockIdx.x * 16;
    const int ncol = n0 + (lane & 15);
    const int nc = ncol < N ? ncol : N - 1;
    const int kg = lane >> 4;
    f32x4 acc[8];
#pragma unroll
    for (int mt = 0; mt < 8; ++mt) acc[mt] = (f32x4)0.f;
    const float* wb = W + (size_t)nc * K + kg * 8;
#pragma unroll
    for (int kc = 0; kc < K / 128; ++kc) {
#pragma unroll
        for (int ksl = 0; ksl < 4; ++ksl) {
            const float* wp = wb + kc * 128 + ksl * 32;
            float4 w0 = *(const float4*)wp;
            float4 w1 = *(const float4*)(wp + 4);
            short8 bf = __builtin_bit_cast(short8, pk8v(w0, w1));
            const uint4* ap = apk + ((size_t)kc * 32 + ksl) * 64 + lane;
#pragma unroll
            for (int mt = 0; mt < 8; ++mt) {
                short8 af = __builtin_bit_cast(short8, ap[mt * 256]);
                acc[mt] = __builtin_amdgcn_mfma_f32_16x16x32_bf16(af, bf, acc[mt], 0, 0, 0);
            }
        }
    }
    const int r0 = (lane >> 4) * 4;
    float bb = (HASB && ncol < N) ? bias[ncol] : 0.f;
    if constexpr (!PACK) {
        if (ncol < N) {
#pragma unroll
            for (int mt = 0; mt < 8; ++mt) {
#pragma unroll
                for (int j = 0; j < 4; ++j) {
                    float v = acc[mt][j] + bb;
                    if (ACT) v = tanhf(v);
                    C[(size_t)(mt * 16 + r0 + j) * N + ncol] = v;
                }
            }
        }
    } else {
        __shared__ float pt[128][17];
#pragma unroll
        for (int mt = 0; mt < 8; ++mt) {
#pragma unroll
            for (int j = 0; j < 4; ++j) {
                float v = acc[mt][j] + bb;
                if (ACT) v = tanhf(v);
                C[(size_t)(mt * 16 + r0 + j) * N + ncol] = v;
                pt[mt * 16 + r0 + j][lane & 15] = v;
            }
        }
        __syncthreads();
#pragma unroll
        for (int i = 0; i < 4; ++i) {
            int fid = i * 64 + lane;       // 256 frags: (row r, half hf)
            int r = fid >> 1, hf = fid & 1;
            int k0 = n0 + hf * 8;          // global k of first elem
            int kc = k0 >> 7, ksl = (k0 >> 5) & 3, kg2 = (k0 >> 3) & 3;
            apk_out[((kc * 8 + (r >> 4)) * 4 + ksl) * 64 + kg2 * 16 + (r & 15)] =
                pk8(&pt[r][hf * 8]);
        }
    }
}

// ---------------------------------------------------------------------------
// K3: GRU gate combine (r,z,n) + pack h fragments (K=512)
// ---------------------------------------------------------------------------
__global__ void k_gru(const float* __restrict__ gi, const float* __restrict__ gh,
                      const float* __restrict__ h0, float* __restrict__ h,
                      uint4* __restrict__ apk_h) {
    __shared__ float hsh[256];
    const int t = threadIdx.x;
    const int idx = blockIdx.x * 256 + t;
    const int b = blockIdx.x >> 1, half = blockIdx.x & 1;
    const int j = half * 256 + t;
    const float* gib = gi + (size_t)b * 1536;
    const float* ghb = gh + (size_t)b * 1536;
    float ir = gib[j], iz = gib[512 + j], inn = gib[1024 + j];
    float hr = ghb[j], hz = ghb[512 + j], hn = ghb[1024 + j];
    float r = 1.f / (1.f + expf(-(ir + hr)));
    float z = 1.f / (1.f + expf(-(iz + hz)));
    float nn = tanhf(inn + r * hn);
    float hv = (1.f - z) * nn + z * h0[idx];
    h[idx] = hv;
    hsh[t] = hv;
    __syncthreads();
    if (t < 32) {
        int k0 = half * 256 + t * 8;
        int kc = k0 >> 7, ksl = (k0 >> 5) & 3, kg = (k0 >> 3) & 3;
        apk_h[((kc * 8 + (b >> 4)) * 4 + ksl) * 64 + kg * 16 + (b & 15)] = pk8(&hsh[t * 8]);
    }
}

// ---------------------------------------------------------------------------
// K4: attention (512 threads): scores (4 lanes/row, shfl reduce) -> mask ->
// softmax -> a[s][b]; ctx accumulate; pack cat=[ctx|h] fragments (K=1024)
// ---------------------------------------------------------------------------
__global__ __launch_bounds__(512) void k_attn(const float* __restrict__ enc,
        const float* __restrict__ q, const int* __restrict__ lens,
        const float* __restrict__ h, float* __restrict__ a_out,
        uint4* __restrict__ apk_cat) {
    __shared__ float qs[512];
    __shared__ float red[128];
    __shared__ float aw[128];
    __shared__ float catsh[1024];
    const int b = blockIdx.x, t = threadIdx.x;
    qs[t] = q[(size_t)b * 512 + t];
    __syncthreads();
    const int srow = t >> 2, part = t & 3;
    const float* ep = enc + ((size_t)b * SRC + srow) * 512 + part * 128;
    float s = 0.f;
#pragma unroll
    for (int k4 = 0; k4 < 32; ++k4) {
        float4 e = ((const float4*)ep)[k4];
        float4 qq = *(const float4*)&qs[part * 128 + k4 * 4];
        s = fmaf(e.x, qq.x, fmaf(e.y, qq.y, fmaf(e.z, qq.z, fmaf(e.w, qq.w, s))));
    }
    s += __shfl_xor(s, 1);
    s += __shfl_xor(s, 2);
    if (part == 0) {
        int len = lens[b];
        float val = (srow < len) ? s : 0.f;
        if (val == 0.f) val = -1e10f;   // replicate ref's where(masked==0,-1e10)
        red[srow] = val;
        aw[srow] = val;
    }
    __syncthreads();
    for (int off = 64; off > 0; off >>= 1) {          // max tree
        if (t < off) red[t] = fmaxf(red[t], red[t + off]);
        __syncthreads();
    }
    float mx = red[0];
    __syncthreads();
    if (t < 128) { float e = expf(aw[t] - mx); aw[t] = e; red[t] = e; }
    __syncthreads();
    for (int off = 64; off > 0; off >>= 1) {          // sum tree
        if (t < off) red[t] += red[t + off];
        __syncthreads();
    }
    float denom = red[0];
    if (t < 128) {
        float av = aw[t] / denom;
        aw[t] = av;
        a_out[(size_t)t * B + b] = av;                // layout [S][B]
    }
    __syncthreads();
    float a0 = 0.f;
    const float* e2 = enc + (size_t)b * (SRC * 512) + t;
#pragma unroll 4
    for (int s2 = 0; s2 < SRC; ++s2) a0 = fmaf(aw[s2], e2[(size_t)s2 * 512], a0);
    catsh[t] = a0;
    catsh[512 + t] = h[(size_t)b * 512 + t];
    __syncthreads();
    if (t < 128) {                                    // pack cat frag (K=1024)
        int kc = t >> 4, ksl = (t >> 2) & 3, kg = t & 3;
        apk_cat[((kc * 8 + (b >> 4)) * 4 + ksl) * 64 + kg * 16 + (b & 15)] =
            pk8(&catsh[t * 8]);
    }
}

// ---------------------------------------------------------------------------
// K5: fc1 GEMM via LDS-staged pre-packed A (global_load_lds, 32KB chunks,
// 4 blocks/CU) + hoisted W streaming. 64 cols/block (16/wave), all 128 m.
// ---------------------------------------------------------------------------
template <int FN, int FK>
__global__ __launch_bounds__(256, 4) void k_fc1(
        const uint4* __restrict__ apk, const float* __restrict__ W,
        const float* __restrict__ bias, float* __restrict__ C) {
    __shared__ uint4 As[2048];   // 32KB: one 128-k chunk of packed A
    const int tid = threadIdx.x, lane = tid & 63, wv = tid >> 6;
    const int ncol = blockIdx.x * 64 + wv * 16 + (lane & 15);
    const int nc = ncol < FN ? ncol : FN - 1;
    const int kg = lane >> 4;
    f32x4 acc[8];
#pragma unroll
    for (int mt = 0; mt < 8; ++mt) acc[mt] = (f32x4)0.f;
    const float* wb = W + (size_t)nc * FK + kg * 8;
#pragma unroll
    for (int kc = 0; kc < FK / 128; ++kc) {
        if (kc) __syncthreads();         // all waves done reading prev chunk
#pragma unroll
        for (int it = 0; it < 8; ++it) { // async stage 32KB (1KB/wave/issue)
            gll16(apk + (size_t)kc * 2048 + it * 256 + wv * 64 + lane,
                  As + it * 256 + wv * 64);
        }
        float4 w[8];
#pragma unroll
        for (int ksl = 0; ksl < 4; ++ksl) {          // hoist W loads
            w[2 * ksl]     = *(const float4*)(wb + kc * 128 + ksl * 32);
            w[2 * ksl + 1] = *(const float4*)(wb + kc * 128 + ksl * 32 + 4);
        }
        __syncthreads();                 // drains DMA (vmcnt 0) + W loads
#pragma unroll
        for (int ksl = 0; ksl < 4; ++ksl) {
            short8 bf = __builtin_bit_cast(short8, pk8v(w[2 * ksl], w[2 * ksl + 1]));
#pragma unroll
            for (int mt = 0; mt < 8; ++mt) {
                short8 af = __builtin_bit_cast(short8, As[(mt * 4 + ksl) * 64 + lane]);
                acc[mt] = __builtin_amdgcn_mfma_f32_16x16x32_bf16(af, bf, acc[mt], 0, 0, 0);
            }
        }
    }
    if (ncol < FN) {
        float bb = bias[ncol];
        const int r0 = (lane >> 4) * 4;
#pragma unroll
        for (int mt = 0; mt < 8; ++mt) {
#pragma unroll
            for (int j = 0; j < 4; ++j)
                C[(size_t)(mt * 16 + r0 + j) * FN + ncol] = acc[mt][j] + bb;
        }
    }
}

// ---------------------------------------------------------------------------
// K6: fused log-softmax (online LSE + in-place subtract)
// ---------------------------------------------------------------------------
__global__ __launch_bounds__(1024) void k_lse_sub(float* __restrict__ logits) {
    const int b = blockIdx.x, t = threadIdx.x;
    float* row = logits + (size_t)b * VOCAB;
    const int N4 = VOCAB >> 2;
    float m = -1e30f, s = 0.f;
    for (int i = t; i < N4; i += 1024) {
        float4 x = ((const float4*)row)[i];
        float xs[4] = {x.x, x.y, x.z, x.w};
#pragma unroll
        for (int j = 0; j < 4; ++j) {
            float v = xs[j];
            if (v > m) { s = s * __expf(m - v) + 1.f; m = v; }
            else        s += __expf(v - m);
        }
    }
    if (t == 0) {
        float v = row[VOCAB - 1];
        if (v > m) { s = s * __expf(m - v) + 1.f; m = v; }
        else        s += __expf(v - m);
    }
    __shared__ float sm[1024], ss[1024];
    sm[t] = m; ss[t] = s;
    __syncthreads();
    for (int off = 512; off > 0; off >>= 1) {
        if (t < off) {
            float m2 = sm[t + off], s2 = ss[t + off];
            float mm = fmaxf(sm[t], m2);
            ss[t] = ss[t] * __expf(sm[t] - mm) + s2 * __expf(m2 - mm);
            sm[t] = mm;
        }
        __syncthreads();
    }
    __shared__ float Lsh;
    if (t == 0) Lsh = sm[0] + logf(ss[0]);
    __syncthreads();
    float L = Lsh;
    for (int i = t; i < N4; i += 1024) {
        float4 x = ((const float4*)row)[i];
        x.x -= L; x.y -= L; x.z -= L; x.w -= L;
        ((float4*)row)[i] = x;
    }
    if (t == 0) row[VOCAB - 1] -= L;
}

// ---------------------------------------------------------------------------
extern "C" void kernel_launch(void* const* d_in, const int* in_sizes, int n_in,
                              void* d_out, int out_size, void* d_ws, size_t ws_size,
                              hipStream_t stream) {
    const int*   x    = (const int*)d_in[0];
    const float* h0   = (const float*)d_in[1];   // decoder_hidden [1,B,H]
    const int*   lens = (const int*)d_in[2];
    const float* enc  = (const float*)d_in[3];   // [B,SRC,H]
    const float* ctxv = (const float*)d_in[4];   // [B,H]
    const float* emb  = (const float*)d_in[5];   // [V,E]
    const float* wih  = (const float*)d_in[6];   // [1536,1024]
    const float* whh  = (const float*)d_in[7];   // [1536,512]
    const float* bih  = (const float*)d_in[8];
    const float* bhh  = (const float*)d_in[9];
    const float* Wa   = (const float*)d_in[10];  // [512,512]
    const float* Wc   = (const float*)d_in[11];  // [512,1024]
    const float* fc1w = (const float*)d_in[12];  // [V,512]
    const float* fc1b = (const float*)d_in[13];

    float* out     = (float*)d_out;
    float* outLogp = out;                                  // [B][VOCAB]
    float* outHid  = out + (size_t)B * VOCAB;              // [B][HID]
    float* outA    = outHid + (size_t)B * HID;             // [SRC][B]
    float* outCtx  = outA + (size_t)SRC * B;               // [B][HID]

    // scratch inside the not-yet-written log_probs region (6.43M floats);
    // everything here is consumed before k_fc1 overwrites the region.
    float* gi = outLogp;                                   // [B][1536]
    float* gh = gi + B * 1536;                             // [B][1536]
    float* q  = gh + B * 1536;                             // [B][512]
    uint4* apk_rnn = (uint4*)(q + B * HID);                // 16384 u4 (K=1024)
    uint4* apk_h0  = apk_rnn + 16384;                      // 8192  u4 (K=512)
    uint4* apk_h   = apk_h0 + 8192;                        // 8192  u4 (K=512)
    uint4* apk_cat = apk_h + 8192;                         // 16384 u4 (K=1024)
    uint4* apk_ctx = (uint4*)d_ws;                         // 8192 u4 = 128KB
                                                           // (survives fc1)

    k_embed_pack<<<dim3(B), dim3(256), 0, stream>>>(x, ctxv, emb, h0, apk_rnn, apk_h0);
    k_gemm_direct<1536, 1024, 0, 1, 0><<<dim3(96), dim3(64), 0, stream>>>(
        apk_rnn, wih, bih, gi, nullptr);
    k_gemm_direct<1536, 512, 0, 1, 0><<<dim3(96), dim3(64), 0, stream>>>(
        apk_h0, whh, bhh, gh, nullptr);
    k_gru<<<dim3(256), dim3(256), 0, stream>>>(gi, gh, h0, outHid, apk_h);
    k_gemm_direct<512, 512, 0, 0, 0><<<dim3(32), dim3(64), 0, stream>>>(
        apk_h, Wa, nullptr, q, nullptr);
    k_attn<<<dim3(B), dim3(512), 0, stream>>>(enc, q, lens, outHid, outA, apk_cat);
    k_gemm_direct<512, 1024, 1, 0, 1><<<dim3(32), dim3(64), 0, stream>>>(
        apk_cat, Wc, nullptr, outCtx, apk_ctx);
    k_fc1<VOCAB, 512><<<dim3(786), dim3(256), 0, stream>>>(apk_ctx, fc1w, fc1b, outLogp);
    k_lse_sub<<<dim3(B), dim3(1024), 0, stream>>>(outLogp);
}